// Round 1
// baseline (884.287 us; speedup 1.0000x reference)
//
#include <hip/hip_runtime.h>

// APPNP block: 10 hops of symmetric-normalized propagation + FFN + residual.
// Strategy: build inverted adjacency (ELL by dst) once per call, then each hop
// is a node-parallel pull (gather+sum, no float atomics). Feature table is
// 19.2MB -> L2/L3 resident, so gathers are cache-served.

constexpr int N      = 100000;
constexpr int E      = 1600000;
constexpr int D      = 48;    // floats per node
constexpr int D4     = 12;    // float4 per node
constexpr int MAXDEG = 64;    // Poisson(16) in-degree; P(any of 100k nodes >= 64) ~ 1e-19

__global__ __launch_bounds__(256) void zero_cnt_kernel(int* __restrict__ cnt) {
    int i = blockIdx.x * 256 + threadIdx.x;
    if (i < N) cnt[i] = 0;
}

__global__ __launch_bounds__(256) void build_ell_kernel(const int* __restrict__ src,
                                                        const int* __restrict__ dst,
                                                        int* __restrict__ cnt,
                                                        int* __restrict__ ell) {
    int e = blockIdx.x * 256 + threadIdx.x;
    if (e >= E) return;
    int d = dst[e];
    int c = atomicAdd(&cnt[d], 1);
    if (c < MAXDEG) ell[d * MAXDEG + c] = src[e];
}

__global__ __launch_bounds__(256) void norm_scaled0_kernel(const int* __restrict__ cnt,
                                                           const float4* __restrict__ feat,
                                                           float* __restrict__ norm,
                                                           float4* __restrict__ sA) {
    int t = blockIdx.x * 256 + threadIdx.x;
    if (t >= N * D4) return;
    int n  = t / D4;
    int f4 = t - n * D4;
    float dg = (float)cnt[n];
    float nm = 1.0f / sqrtf(fmaxf(dg, 1.0f));
    if (f4 == 0) norm[n] = nm;
    float4 v = feat[t];
    float4 o;
    o.x = v.x * nm; o.y = v.y * nm; o.z = v.z * nm; o.w = v.w * nm;
    sA[t] = o;
}

// One thread per (node, float4-chunk). 12 consecutive lanes read one source
// node's 192B row contiguously. h_new = 0.9*(sum*norm) + 0.1*h0; intermediate
// h is never needed, only scaled = h*norm (except the last hop -> r output).
template <bool LAST>
__global__ __launch_bounds__(256) void agg_kernel(const float4* __restrict__ scaled_in,
                                                  const int* __restrict__ ell,
                                                  const int* __restrict__ cnt,
                                                  const float* __restrict__ norm,
                                                  const float4* __restrict__ h0,
                                                  float4* __restrict__ scaled_out,
                                                  float4* __restrict__ h_out) {
    int t = blockIdx.x * 256 + threadIdx.x;
    if (t >= N * D4) return;
    int n  = t / D4;
    int f4 = t - n * D4;
    int deg = cnt[n];
    deg = deg > MAXDEG ? MAXDEG : deg;   // never read unwritten (poisoned) slots
    float nm = norm[n];
    const int* row = ell + n * MAXDEG;
    float sx = 0.f, sy = 0.f, sz = 0.f, sw = 0.f;
    for (int j = 0; j < deg; ++j) {
        int sn = row[j];
        float4 v = scaled_in[sn * D4 + f4];
        sx += v.x; sy += v.y; sz += v.z; sw += v.w;
    }
    float4 h0v = h0[t];
    float4 hv;
    hv.x = 0.9f * (sx * nm) + 0.1f * h0v.x;
    hv.y = 0.9f * (sy * nm) + 0.1f * h0v.y;
    hv.z = 0.9f * (sz * nm) + 0.1f * h0v.z;
    hv.w = 0.9f * (sw * nm) + 0.1f * h0v.w;
    if (LAST) {
        h_out[t] = hv;
    } else {
        float4 sc;
        sc.x = hv.x * nm; sc.y = hv.y * nm; sc.z = hv.z * nm; sc.w = hv.w * nm;
        scaled_out[t] = sc;
    }
}

// rst = relu(h@w1 + b1)@w2 + b2 + features. Thread-per-node, weights in LDS,
// fully unrolled 48-wide register accumulators (~921 MFLOP total, noise).
__global__ __launch_bounds__(256) void ffn_kernel(const float* __restrict__ r,
                                                  const float4* __restrict__ feat,
                                                  const float* __restrict__ w1,
                                                  const float* __restrict__ b1,
                                                  const float* __restrict__ w2,
                                                  const float* __restrict__ b2,
                                                  float4* __restrict__ rst) {
    __shared__ __align__(16) float sw1[D * D];
    __shared__ __align__(16) float sw2[D * D];
    __shared__ float sb1[D], sb2[D];
    for (int i = threadIdx.x; i < D * D; i += 256) {
        sw1[i] = w1[i];
        sw2[i] = w2[i];
    }
    if (threadIdx.x < D) {
        sb1[threadIdx.x] = b1[threadIdx.x];
        sb2[threadIdx.x] = b2[threadIdx.x];
    }
    __syncthreads();

    int n = blockIdx.x * 256 + threadIdx.x;
    if (n >= N) return;

    float h[D];
    const float4* r4 = (const float4*)(r + (size_t)n * D);
#pragma unroll
    for (int i = 0; i < D4; ++i) {
        float4 v = r4[i];
        h[4 * i + 0] = v.x; h[4 * i + 1] = v.y; h[4 * i + 2] = v.z; h[4 * i + 3] = v.w;
    }

    float hid[D];
#pragma unroll
    for (int j = 0; j < D; ++j) hid[j] = sb1[j];
    for (int k = 0; k < D; ++k) {
        float hk = h[k];
        const float4* wrow = (const float4*)(sw1 + k * D);
#pragma unroll
        for (int jc = 0; jc < D4; ++jc) {
            float4 wv = wrow[jc];
            hid[4 * jc + 0] += hk * wv.x;
            hid[4 * jc + 1] += hk * wv.y;
            hid[4 * jc + 2] += hk * wv.z;
            hid[4 * jc + 3] += hk * wv.w;
        }
    }
#pragma unroll
    for (int j = 0; j < D; ++j) hid[j] = fmaxf(hid[j], 0.0f);

    // reuse h[] as the second-layer accumulator
#pragma unroll
    for (int j = 0; j < D; ++j) h[j] = sb2[j];
    for (int k = 0; k < D; ++k) {
        float hk = hid[k];
        const float4* wrow = (const float4*)(sw2 + k * D);
#pragma unroll
        for (int jc = 0; jc < D4; ++jc) {
            float4 wv = wrow[jc];
            h[4 * jc + 0] += hk * wv.x;
            h[4 * jc + 1] += hk * wv.y;
            h[4 * jc + 2] += hk * wv.z;
            h[4 * jc + 3] += hk * wv.w;
        }
    }

#pragma unroll
    for (int i = 0; i < D4; ++i) {
        float4 fv = feat[(size_t)n * D4 + i];
        float4 o;
        o.x = h[4 * i + 0] + fv.x;
        o.y = h[4 * i + 1] + fv.y;
        o.z = h[4 * i + 2] + fv.z;
        o.w = h[4 * i + 3] + fv.w;
        rst[(size_t)n * D4 + i] = o;
    }
}

extern "C" void kernel_launch(void* const* d_in, const int* in_sizes, int n_in,
                              void* d_out, int out_size, void* d_ws, size_t ws_size,
                              hipStream_t stream) {
    const float* feat = (const float*)d_in[0];
    const int*   src  = (const int*)d_in[1];
    const int*   dst  = (const int*)d_in[2];
    const float* w1   = (const float*)d_in[3];
    const float* b1   = (const float*)d_in[4];
    const float* w2   = (const float*)d_in[5];
    const float* b2   = (const float*)d_in[6];

    float* rst   = (float*)d_out;                  // output 0: [N, D]
    float* r_out = rst + (size_t)N * D;            // output 1: [N, D]

    // workspace layout (all 16B-aligned offsets)
    char*  w    = (char*)d_ws;
    int*   cnt  = (int*)w;                                   // 400,000 B
    float* norm = (float*)(w + 400000);                      // 400,000 B
    int*   ell  = (int*)(w + 800000);                        // 25,600,000 B
    float* sA   = (float*)(w + 800000 + 25600000);           // 19,200,000 B
    float* sB   = sA + (size_t)N * D;                        // 19,200,000 B

    zero_cnt_kernel<<<(N + 255) / 256, 256, 0, stream>>>(cnt);
    build_ell_kernel<<<(E + 255) / 256, 256, 0, stream>>>(src, dst, cnt, ell);
    norm_scaled0_kernel<<<(N * D4 + 255) / 256, 256, 0, stream>>>(
        cnt, (const float4*)feat, norm, (float4*)sA);

    float* bufs[2] = {sA, sB};
    for (int hop = 0; hop < 10; ++hop) {
        const float4* in  = (const float4*)bufs[hop & 1];
        float4*       out = (float4*)bufs[(hop + 1) & 1];
        if (hop < 9) {
            agg_kernel<false><<<(N * D4 + 255) / 256, 256, 0, stream>>>(
                in, ell, cnt, norm, (const float4*)feat, out, nullptr);
        } else {
            agg_kernel<true><<<(N * D4 + 255) / 256, 256, 0, stream>>>(
                in, ell, cnt, norm, (const float4*)feat, nullptr, (float4*)r_out);
        }
    }

    ffn_kernel<<<(N + 255) / 256, 256, 0, stream>>>(
        r_out, (const float4*)feat, w1, b1, w2, b2, (float4*)rst);
}

// Round 2
// 659.925 us; speedup vs baseline: 1.3400x; 1.3400x over previous
//
#include <hip/hip_runtime.h>

// APPNP block: 10 hops of symmetric-normalized propagation + FFN + residual.
// Round 2: ping-pong "scaled" buffers stored as bf16 (halves the dominant
// random-gather traffic: 307 -> 154 MB/hop). 6 lanes/node x 16B loads,
// neighbor loop unrolled x4 for memory-level parallelism. All accumulation,
// norm, h0, and outputs remain fp32.

constexpr int N      = 100000;
constexpr int E      = 1600000;
constexpr int D      = 48;    // floats per node
constexpr int D4     = 12;    // float4 per node (fp32 views)
constexpr int C8     = 6;     // chunks of 8 bf16 (16B) per node
constexpr int MAXDEG = 64;    // Poisson(16) in-degree; P(any >= 64) ~ 1e-19

typedef unsigned int uint;

__device__ __forceinline__ uint pack_bf16x2(float x, float y) {
    uint bx = __float_as_uint(x), by = __float_as_uint(y);
    bx = (bx + 0x7FFFu + ((bx >> 16) & 1u)) >> 16;          // RNE
    by = (by + 0x7FFFu + ((by >> 16) & 1u)) >> 16;
    return bx | (by << 16);
}

__device__ __forceinline__ void unpack_add(uint u, float& a0, float& a1) {
    a0 += __uint_as_float(u << 16);
    a1 += __uint_as_float(u & 0xFFFF0000u);
}

__global__ __launch_bounds__(256) void zero_cnt_kernel(int* __restrict__ cnt) {
    int i = blockIdx.x * 256 + threadIdx.x;
    if (i < N) cnt[i] = 0;
}

__global__ __launch_bounds__(256) void build_ell_kernel(const int* __restrict__ src,
                                                        const int* __restrict__ dst,
                                                        int* __restrict__ cnt,
                                                        int* __restrict__ ell) {
    int e = blockIdx.x * 256 + threadIdx.x;
    if (e >= E) return;
    int d = dst[e];
    int c = atomicAdd(&cnt[d], 1);
    if (c < MAXDEG) ell[d * MAXDEG + c] = src[e];
}

// scaled0 = feat * norm, packed to bf16 (uint4 = 8 bf16 per thread chunk).
__global__ __launch_bounds__(256) void norm_scaled0_kernel(const int* __restrict__ cnt,
                                                           const float4* __restrict__ feat,
                                                           float* __restrict__ norm,
                                                           uint4* __restrict__ sA) {
    int t = blockIdx.x * 256 + threadIdx.x;
    if (t >= N * C8) return;
    int n = t / C8;
    int c = t - n * C8;
    float dg = (float)cnt[n];
    float nm = 1.0f / sqrtf(fmaxf(dg, 1.0f));
    if (c == 0) norm[n] = nm;
    float4 v0 = feat[n * D4 + c * 2];
    float4 v1 = feat[n * D4 + c * 2 + 1];
    uint4 o;
    o.x = pack_bf16x2(v0.x * nm, v0.y * nm);
    o.y = pack_bf16x2(v0.z * nm, v0.w * nm);
    o.z = pack_bf16x2(v1.x * nm, v1.y * nm);
    o.w = pack_bf16x2(v1.z * nm, v1.w * nm);
    sA[t] = o;
}

// One thread per (node, 8-float chunk). 6 consecutive lanes read one source
// node's 96B bf16 row contiguously. Neighbor loop unrolled x4 -> 4 outstanding
// 16B gathers per thread. h_new = 0.9*(sum*norm) + 0.1*h0.
template <bool LAST>
__global__ __launch_bounds__(256) void agg_kernel(const uint4* __restrict__ scaled_in,
                                                  const int* __restrict__ ell,
                                                  const int* __restrict__ cnt,
                                                  const float* __restrict__ norm,
                                                  const float4* __restrict__ h0,
                                                  uint4* __restrict__ scaled_out,
                                                  float4* __restrict__ h_out) {
    int t = blockIdx.x * 256 + threadIdx.x;
    if (t >= N * C8) return;
    int n = t / C8;
    int c = t - n * C8;
    int deg = cnt[n];
    deg = deg > MAXDEG ? MAXDEG : deg;   // never read unwritten (poisoned) slots
    float nm = norm[n];
    const int* row = ell + n * MAXDEG;

    float a0 = 0.f, a1 = 0.f, a2 = 0.f, a3 = 0.f,
          a4 = 0.f, a5 = 0.f, a6 = 0.f, a7 = 0.f;

    int j = 0;
    for (; j + 3 < deg; j += 4) {
        int s0 = row[j], s1 = row[j + 1], s2 = row[j + 2], s3 = row[j + 3];
        uint4 v0 = scaled_in[s0 * C8 + c];
        uint4 v1 = scaled_in[s1 * C8 + c];
        uint4 v2 = scaled_in[s2 * C8 + c];
        uint4 v3 = scaled_in[s3 * C8 + c];
        unpack_add(v0.x, a0, a1); unpack_add(v0.y, a2, a3);
        unpack_add(v0.z, a4, a5); unpack_add(v0.w, a6, a7);
        unpack_add(v1.x, a0, a1); unpack_add(v1.y, a2, a3);
        unpack_add(v1.z, a4, a5); unpack_add(v1.w, a6, a7);
        unpack_add(v2.x, a0, a1); unpack_add(v2.y, a2, a3);
        unpack_add(v2.z, a4, a5); unpack_add(v2.w, a6, a7);
        unpack_add(v3.x, a0, a1); unpack_add(v3.y, a2, a3);
        unpack_add(v3.z, a4, a5); unpack_add(v3.w, a6, a7);
    }
    for (; j < deg; ++j) {
        uint4 v = scaled_in[row[j] * C8 + c];
        unpack_add(v.x, a0, a1); unpack_add(v.y, a2, a3);
        unpack_add(v.z, a4, a5); unpack_add(v.w, a6, a7);
    }

    float4 h0a = h0[n * D4 + c * 2];
    float4 h0b = h0[n * D4 + c * 2 + 1];
    float h0v[8] = {h0a.x, h0a.y, h0a.z, h0a.w, h0b.x, h0b.y, h0b.z, h0b.w};
    float hv[8] = {a0, a1, a2, a3, a4, a5, a6, a7};
#pragma unroll
    for (int i = 0; i < 8; ++i) hv[i] = 0.9f * (hv[i] * nm) + 0.1f * h0v[i];

    if (LAST) {
        float4 o0 = {hv[0], hv[1], hv[2], hv[3]};
        float4 o1 = {hv[4], hv[5], hv[6], hv[7]};
        h_out[n * D4 + c * 2]     = o0;
        h_out[n * D4 + c * 2 + 1] = o1;
    } else {
        uint4 o;
        o.x = pack_bf16x2(hv[0] * nm, hv[1] * nm);
        o.y = pack_bf16x2(hv[2] * nm, hv[3] * nm);
        o.z = pack_bf16x2(hv[4] * nm, hv[5] * nm);
        o.w = pack_bf16x2(hv[6] * nm, hv[7] * nm);
        scaled_out[t] = o;
    }
}

// rst = relu(h@w1 + b1)@w2 + b2 + features. Thread-per-node, weights in LDS,
// fully unrolled 48-wide register accumulators (~921 MFLOP total, noise).
__global__ __launch_bounds__(256) void ffn_kernel(const float* __restrict__ r,
                                                  const float4* __restrict__ feat,
                                                  const float* __restrict__ w1,
                                                  const float* __restrict__ b1,
                                                  const float* __restrict__ w2,
                                                  const float* __restrict__ b2,
                                                  float4* __restrict__ rst) {
    __shared__ __align__(16) float sw1[D * D];
    __shared__ __align__(16) float sw2[D * D];
    __shared__ float sb1[D], sb2[D];
    for (int i = threadIdx.x; i < D * D; i += 256) {
        sw1[i] = w1[i];
        sw2[i] = w2[i];
    }
    if (threadIdx.x < D) {
        sb1[threadIdx.x] = b1[threadIdx.x];
        sb2[threadIdx.x] = b2[threadIdx.x];
    }
    __syncthreads();

    int n = blockIdx.x * 256 + threadIdx.x;
    if (n >= N) return;

    float h[D];
    const float4* r4 = (const float4*)(r + (size_t)n * D);
#pragma unroll
    for (int i = 0; i < D4; ++i) {
        float4 v = r4[i];
        h[4 * i + 0] = v.x; h[4 * i + 1] = v.y; h[4 * i + 2] = v.z; h[4 * i + 3] = v.w;
    }

    float hid[D];
#pragma unroll
    for (int j = 0; j < D; ++j) hid[j] = sb1[j];
    for (int k = 0; k < D; ++k) {
        float hk = h[k];
        const float4* wrow = (const float4*)(sw1 + k * D);
#pragma unroll
        for (int jc = 0; jc < D4; ++jc) {
            float4 wv = wrow[jc];
            hid[4 * jc + 0] += hk * wv.x;
            hid[4 * jc + 1] += hk * wv.y;
            hid[4 * jc + 2] += hk * wv.z;
            hid[4 * jc + 3] += hk * wv.w;
        }
    }
#pragma unroll
    for (int j = 0; j < D; ++j) hid[j] = fmaxf(hid[j], 0.0f);

#pragma unroll
    for (int j = 0; j < D; ++j) h[j] = sb2[j];
    for (int k = 0; k < D; ++k) {
        float hk = hid[k];
        const float4* wrow = (const float4*)(sw2 + k * D);
#pragma unroll
        for (int jc = 0; jc < D4; ++jc) {
            float4 wv = wrow[jc];
            h[4 * jc + 0] += hk * wv.x;
            h[4 * jc + 1] += hk * wv.y;
            h[4 * jc + 2] += hk * wv.z;
            h[4 * jc + 3] += hk * wv.w;
        }
    }

#pragma unroll
    for (int i = 0; i < D4; ++i) {
        float4 fv = feat[(size_t)n * D4 + i];
        float4 o;
        o.x = h[4 * i + 0] + fv.x;
        o.y = h[4 * i + 1] + fv.y;
        o.z = h[4 * i + 2] + fv.z;
        o.w = h[4 * i + 3] + fv.w;
        rst[(size_t)n * D4 + i] = o;
    }
}

extern "C" void kernel_launch(void* const* d_in, const int* in_sizes, int n_in,
                              void* d_out, int out_size, void* d_ws, size_t ws_size,
                              hipStream_t stream) {
    const float* feat = (const float*)d_in[0];
    const int*   src  = (const int*)d_in[1];
    const int*   dst  = (const int*)d_in[2];
    const float* w1   = (const float*)d_in[3];
    const float* b1   = (const float*)d_in[4];
    const float* w2   = (const float*)d_in[5];
    const float* b2   = (const float*)d_in[6];

    float* rst   = (float*)d_out;                  // output 0: [N, D]
    float* r_out = rst + (size_t)N * D;            // output 1: [N, D]

    // workspace layout (16B-aligned offsets)
    char*  w    = (char*)d_ws;
    int*   cnt  = (int*)w;                                   //   400,000 B
    float* norm = (float*)(w + 400000);                      //   400,000 B
    int*   ell  = (int*)(w + 800000);                        // 25,600,000 B
    uint4* sA   = (uint4*)(w + 800000 + 25600000);           //  9,600,000 B
    uint4* sB   = sA + (size_t)N * C8;                       //  9,600,000 B

    zero_cnt_kernel<<<(N + 255) / 256, 256, 0, stream>>>(cnt);
    build_ell_kernel<<<(E + 255) / 256, 256, 0, stream>>>(src, dst, cnt, ell);
    norm_scaled0_kernel<<<(N * C8 + 255) / 256, 256, 0, stream>>>(
        cnt, (const float4*)feat, norm, sA);

    uint4* bufs[2] = {sA, sB};
    for (int hop = 0; hop < 10; ++hop) {
        const uint4* in  = bufs[hop & 1];
        uint4*       out = bufs[(hop + 1) & 1];
        if (hop < 9) {
            agg_kernel<false><<<(N * C8 + 255) / 256, 256, 0, stream>>>(
                in, ell, cnt, norm, (const float4*)feat, out, nullptr);
        } else {
            agg_kernel<true><<<(N * C8 + 255) / 256, 256, 0, stream>>>(
                in, ell, cnt, norm, (const float4*)feat, nullptr, (float4*)r_out);
        }
    }

    ffn_kernel<<<(N + 255) / 256, 256, 0, stream>>>(
        r_out, (const float4*)feat, w1, b1, w2, b2, (float4*)rst);
}